// Round 11
// baseline (131.782 us; speedup 1.0000x reference)
//
#include <hip/hip_runtime.h>
#include <hip/hip_bf16.h>
#include <stdint.h>

typedef __attribute__((ext_vector_type(8))) short short8;
typedef __attribute__((ext_vector_type(4))) float f32x4;
typedef unsigned short u16;

#define AS1 __attribute__((address_space(1)))
#define AS3 __attribute__((address_space(3)))

__device__ __forceinline__ u16 f2b(float f) {
  union { float f; uint32_t u; } c; c.f = f;
  uint32_t u = c.u;
  return (u16)((u + 0x7fffu + ((u >> 16) & 1u)) >> 16);  // RNE
}
__device__ __forceinline__ float b2f(u16 b) {
  union { uint32_t u; float f; } c; c.u = ((uint32_t)b) << 16;
  return c.f;
}

// ---------------- conversion kernels (verified round 1) ----------------
__global__ void cvt_bf16_kernel(const float* __restrict__ src,
                                u16* __restrict__ dst, int n4) {
  int i = blockIdx.x * blockDim.x + threadIdx.x;
  if (i >= n4) return;
  const float4 v = reinterpret_cast<const float4*>(src)[i];
  ushort4 o;
  o.x = f2b(v.x); o.y = f2b(v.y); o.z = f2b(v.z); o.w = f2b(v.w);
  reinterpret_cast<ushort4*>(dst)[i] = o;
}

__global__ void cvt_transpose_kernel(const float* __restrict__ w0,
                                     const float* __restrict__ w1,
                                     const float* __restrict__ w2,
                                     u16* __restrict__ d0,
                                     u16* __restrict__ d1,
                                     u16* __restrict__ d2,
                                     int K, int N) {
  const float* src = (blockIdx.y == 0) ? w0 : (blockIdx.y == 1 ? w1 : w2);
  u16* dst = (blockIdx.y == 0) ? d0 : (blockIdx.y == 1 ? d1 : d2);
  int idx = blockIdx.x * blockDim.x + threadIdx.x;
  if (idx >= K * N) return;
  int k = idx / N, n = idx - k * N;
  dst[(size_t)n * K + k] = f2b(src[idx]);
}

// ---- 256-wide-tile, BK=32, 4-buf, read-ahead counted-wait GEMM ----
// Staging-byte model (r10 post-mortem): staged = 2KMN(1/BM+1/BN); the
// global_load_lds wall is ~18.8 B/cyc/CU (r10-gates == m201).  256-wide
// tiles halve the bytes vs 128^2.  BK=32, NT=32 tiles, 512 thr = 8 waves
// 2Mx4N, per-wave 128 x (BN/4).  LDS = 4 bufs x (A 16KB + B BN/16 KB);
// tile t lives in buf[t&3].  Schedule per tile (2 phases, 1 barrier each):
//  ph(t,0): RD aHI(t) [4]; STG A(t+3) [2]; lgkm(4) -> aLO(t),b(t) ready;
//           MFMA aLO(t)xb(t); VMW(cnt) [drains tile t+1's stages]; BAR
//  ph(t,1): RD aLO(t+1)+b(t+1) [from buf (t+1)&3, landed+barriered];
//           STG B(t+3); lgkm(own) -> aHI ready; MFMA aHI(t)xb(t); BAR
// vmcnt queue (per wave, in-order): ..A(t+1),B(t+1),A(t+2),B(t+2),A(t+3);
// VMW leaves the newest {A(t+2),B(t+2),A(t+3)} (6 insts gates / 5 cand) =>
// A(t+1),B(t+1) landed before the barrier that precedes their reads.
// Prefetch distance ~3 phases (>2000 cyc) >> L2/HBM latency.  Tail t>=29:
// full drain (3 tiles, negligible).  WAR: stage into buf[(t+3)&3] ==
// buf[(t-1)&3]; A-region last read-issue ph(t-1,0), retired by lgkm at
// ph(t-1,1) pre-barrier, STG_A at ph(t,0) is 1+ barrier later; B-region
// last read ph(t-2,1), retired ph(t-1,0), STG_B at ph(t,1): 2+ barriers.
// Swizzle: 64B rows, slot ^= (row>>1)&3 (r3-verified, 0 bank conflicts).
// Registers: operands 20 frags (gates) / 16 (cand) x 4 VGPR -> fits the
// observed 128-VGPR cap; acc in AGPR (128 / 64).  No spill by design.

#define BAR() __builtin_amdgcn_s_barrier()
#define SB() __builtin_amdgcn_sched_barrier(0)
#define LG(n) do { asm volatile("s_waitcnt lgkmcnt(" #n ")" ::: "memory"); __builtin_amdgcn_sched_barrier(0); } while (0)
#define VMW(n) do { asm volatile("s_waitcnt vmcnt(" #n ")" ::: "memory"); __builtin_amdgcn_sched_barrier(0); } while (0)

// ---------------- GATES: C[16384,1024] = [x|h] @ [Wz^T;Wr^T]^T ----------
__global__ __launch_bounds__(512, 1) void gates_k(
    const u16* __restrict__ xb, const u16* __restrict__ hb,
    const u16* __restrict__ wt,
    u16* __restrict__ o_z, u16* __restrict__ o_rh) {
  constexpr int NT = 32;
  __shared__ u16 lds[65536];            // 4 bufs x 32768 B
  const char* ldsb = (const char*)lds;

  const int tid = threadIdx.x, lane = tid & 63, wid = tid >> 6;
  const int wm = wid >> 2, wn = wid & 3;
  const int wg = ((int)blockIdx.x & 7) * 32 + ((int)blockIdx.x >> 3);
  const int bn = wg & 3, bm = wg >> 2;

  const int srow = tid >> 2;                               // 0..127
  const int scol = ((tid & 3) ^ ((tid >> 3) & 3)) << 4;    // swizzled slot

  auto STG_A = [&](int t) {
    if (t >= NT) return;
    char* dst = (char*)lds + (t & 3) * 32768 + wid * 1024;
    const char* base = (t < 16) ? ((const char*)xb + (size_t)t * 64)
                                : ((const char*)hb + (size_t)(t - 16) * 64);
#pragma unroll
    for (int i = 0; i < 2; ++i) {
      const char* src = base + (size_t)(bm * 256 + i * 128 + srow) * 1024 + scol;
      __builtin_amdgcn_global_load_lds((const AS1 void*)src,
                                       (AS3 void*)(dst + i * 8192), 16, 0, 0);
    }
  };
  auto STG_B = [&](int t) {
    if (t >= NT) return;
    char* dst = (char*)lds + (t & 3) * 32768 + 16384 + wid * 1024;
#pragma unroll
    for (int i = 0; i < 2; ++i) {
      const char* src = (const char*)wt +
                        (size_t)(bn * 256 + i * 128 + srow) * 2048 +
                        (size_t)t * 64 + scol;
      __builtin_amdgcn_global_load_lds((const AS1 void*)src,
                                       (AS3 void*)(dst + i * 8192), 16, 0, 0);
    }
  };

  const int rsel = lane & 15, kg = lane >> 4;
  const int rcol = (kg ^ ((rsel >> 1) & 3)) << 4;
  const int aoff = (wm * 128 + rsel) * 64 + rcol;          // + mf*1024
  const int boff = 16384 + (wn * 64 + rsel) * 64 + rcol;   // + nf*1024

  f32x4 acc[8][4] = {};
  short8 aL0[4], aL1[4], aH[4], b0[4], b1[4];

  auto RD_ALO = [&](auto& d, int t) {
    const char* p = ldsb + (t & 3) * 32768;
#pragma unroll
    for (int i = 0; i < 4; ++i) d[i] = *(const short8*)(p + aoff + i * 1024);
  };
  auto RD_AHI = [&](int t) {
    const char* p = ldsb + (t & 3) * 32768;
#pragma unroll
    for (int i = 0; i < 4; ++i) aH[i] = *(const short8*)(p + aoff + (4 + i) * 1024);
  };
  auto RD_B = [&](auto& d, int t) {
    const char* p = ldsb + (t & 3) * 32768;
#pragma unroll
    for (int i = 0; i < 4; ++i) d[i] = *(const short8*)(p + boff + i * 1024);
  };
  auto MM = [&](auto& A, auto& Bv, int mb) {
    __builtin_amdgcn_s_setprio(1);
#pragma unroll
    for (int mi = 0; mi < 4; ++mi)
#pragma unroll
      for (int ni = 0; ni < 4; ++ni)
        acc[mb + mi][ni] = __builtin_amdgcn_mfma_f32_16x16x32_bf16(
            A[mi], Bv[ni], acc[mb + mi][ni], 0, 0, 0);
    __builtin_amdgcn_s_setprio(0);
  };

  // prologue: tiles 0,1,2 staged; t0,t1 landed; pre-read aLO(0), b(0)
  STG_A(0); STG_B(0); STG_A(1); STG_B(1); STG_A(2); STG_B(2);
  VMW(4); BAR();
  RD_ALO(aL0, 0); RD_B(b0, 0); SB();

#pragma unroll 1
  for (int j = 0; j < NT / 2; ++j) {
    const int te = 2 * j, to = 2 * j + 1;
    // ph(te,0)
    RD_AHI(te); STG_A(te + 3);
    LG(4); MM(aL0, b0, 0);
    if (te < 29) { VMW(6); } else { VMW(0); }
    BAR();
    // ph(te,1)
    RD_ALO(aL1, to); RD_B(b1, to); STG_B(te + 3);
    LG(8); MM(aH, b0, 4);
    BAR();
    // ph(to,0)
    RD_AHI(to); STG_A(to + 3);
    LG(4); MM(aL1, b1, 0);
    if (to < 29) { VMW(6); } else { VMW(0); }
    BAR();
    // ph(to,1)
    if (j < NT / 2 - 1) {
      RD_ALO(aL0, to + 1); RD_B(b0, to + 1); STG_B(to + 3);
      LG(8); MM(aH, b1, 4);
    } else {
      LG(0); MM(aH, b1, 4);
    }
    BAR();
  }

  // epilogue (r5-verified layout; bf16 h numerics r6-verified)
  const int row0 = bm * 256 + wm * 128 + kg * 4;
  const int col0 = bn * 256 + wn * 64 + rsel;
  if (bn < 2) {  // z half (global cols 0..511)
#pragma unroll
    for (int mf = 0; mf < 8; ++mf)
#pragma unroll
      for (int nf = 0; nf < 4; ++nf)
#pragma unroll
        for (int q = 0; q < 4; ++q) {
          const int row = row0 + mf * 16 + q;
          const int col = col0 + nf * 16;
          const float zf = 1.f / (1.f + __expf(-acc[mf][nf][q]));
          o_z[(size_t)row * 512 + col] = f2b(zf);
        }
  } else {       // r half (global cols 512..1023)
#pragma unroll
    for (int mf = 0; mf < 8; ++mf)
#pragma unroll
      for (int nf = 0; nf < 4; ++nf)
#pragma unroll
        for (int q = 0; q < 4; ++q) {
          const int row = row0 + mf * 16 + q;
          const int col = col0 + nf * 16 - 512;
          const size_t idx = (size_t)row * 512 + col;
          const float rf = 1.f / (1.f + __expf(-acc[mf][nf][q]));
          o_rh[idx] = f2b(rf * b2f(hb[idx]));
        }
  }
}

// ---------------- CAND: C[16384,512] = [x|rh] @ Wh^T; fuse output -------
__global__ __launch_bounds__(512, 1) void cand_k(
    const u16* __restrict__ xb, const u16* __restrict__ rhb,
    const u16* __restrict__ wt, const u16* __restrict__ hb,
    const u16* __restrict__ zb_in, float* __restrict__ o_f) {
  constexpr int NT = 32;
  __shared__ u16 lds[49152];            // 4 bufs x 24576 B
  const char* ldsb = (const char*)lds;

  const int tid = threadIdx.x, lane = tid & 63, wid = tid >> 6;
  const int wm = wid >> 2, wn = wid & 3;
  const int wg = ((int)blockIdx.x & 7) * 32 + ((int)blockIdx.x >> 3);
  const int bn = wg & 3, bm = wg >> 2;

  const int srow = tid >> 2;
  const int scol = ((tid & 3) ^ ((tid >> 3) & 3)) << 4;

  auto STG_A = [&](int t) {
    if (t >= NT) return;
    char* dst = (char*)lds + (t & 3) * 24576 + wid * 1024;
    const char* base = (t < 16) ? ((const char*)xb + (size_t)t * 64)
                                : ((const char*)rhb + (size_t)(t - 16) * 64);
#pragma unroll
    for (int i = 0; i < 2; ++i) {
      const char* src = base + (size_t)(bm * 256 + i * 128 + srow) * 1024 + scol;
      __builtin_amdgcn_global_load_lds((const AS1 void*)src,
                                       (AS3 void*)(dst + i * 8192), 16, 0, 0);
    }
  };
  auto STG_B = [&](int t) {   // 1 inst: B tile 128 rows x 64 B
    if (t >= NT) return;
    char* dst = (char*)lds + (t & 3) * 24576 + 16384 + wid * 1024;
    const char* src = (const char*)wt +
                      (size_t)(bn * 128 + srow) * 2048 + (size_t)t * 64 + scol;
    __builtin_amdgcn_global_load_lds((const AS1 void*)src, (AS3 void*)dst, 16, 0, 0);
  };

  const int rsel = lane & 15, kg = lane >> 4;
  const int rcol = (kg ^ ((rsel >> 1) & 3)) << 4;
  const int aoff = (wm * 128 + rsel) * 64 + rcol;
  const int boff = 16384 + (wn * 32 + rsel) * 64 + rcol;

  f32x4 acc[8][2] = {};
  short8 aL0[4], aL1[4], aH[4], b0[2], b1[2];

  auto RD_ALO = [&](auto& d, int t) {
    const char* p = ldsb + (t & 3) * 24576;
#pragma unroll
    for (int i = 0; i < 4; ++i) d[i] = *(const short8*)(p + aoff + i * 1024);
  };
  auto RD_AHI = [&](int t) {
    const char* p = ldsb + (t & 3) * 24576;
#pragma unroll
    for (int i = 0; i < 4; ++i) aH[i] = *(const short8*)(p + aoff + (4 + i) * 1024);
  };
  auto RD_B = [&](auto& d, int t) {
    const char* p = ldsb + (t & 3) * 24576;
#pragma unroll
    for (int i = 0; i < 2; ++i) d[i] = *(const short8*)(p + boff + i * 1024);
  };
  auto MM = [&](auto& A, auto& Bv, int mb) {
    __builtin_amdgcn_s_setprio(1);
#pragma unroll
    for (int mi = 0; mi < 4; ++mi)
#pragma unroll
      for (int ni = 0; ni < 2; ++ni)
        acc[mb + mi][ni] = __builtin_amdgcn_mfma_f32_16x16x32_bf16(
            A[mi], Bv[ni], acc[mb + mi][ni], 0, 0, 0);
    __builtin_amdgcn_s_setprio(0);
  };

  STG_A(0); STG_B(0); STG_A(1); STG_B(1); STG_A(2); STG_B(2);
  VMW(3); BAR();
  RD_ALO(aL0, 0); RD_B(b0, 0); SB();

#pragma unroll 1
  for (int j = 0; j < NT / 2; ++j) {
    const int te = 2 * j, to = 2 * j + 1;
    // ph(te,0)
    RD_AHI(te); STG_A(te + 3);
    LG(4); MM(aL0, b0, 0);
    if (te < 29) { VMW(5); } else { VMW(0); }
    BAR();
    // ph(te,1)
    RD_ALO(aL1, to); RD_B(b1, to); STG_B(te + 3);
    LG(6); MM(aH, b0, 4);
    BAR();
    // ph(to,0)
    RD_AHI(to); STG_A(to + 3);
    LG(4); MM(aL1, b1, 0);
    if (to < 29) { VMW(5); } else { VMW(0); }
    BAR();
    // ph(to,1)
    if (j < NT / 2 - 1) {
      RD_ALO(aL0, to + 1); RD_B(b0, to + 1); STG_B(to + 3);
      LG(6); MM(aH, b1, 4);
    } else {
      LG(0); MM(aH, b1, 4);
    }
    BAR();
  }

  // epilogue (r7-verified): out = z*h + (1-z)*tanh(s)
  const int row0 = bm * 256 + wm * 128 + kg * 4;
  const int col0 = bn * 128 + wn * 32 + rsel;
#pragma unroll
  for (int mf = 0; mf < 8; ++mf)
#pragma unroll
    for (int nf = 0; nf < 2; ++nf)
#pragma unroll
      for (int q = 0; q < 4; ++q) {
        const int row = row0 + mf * 16 + q;
        const int col = col0 + nf * 16;
        const size_t idx = (size_t)row * 512 + col;
        const float s = acc[mf][nf][q];
        const float hh = 2.f / (1.f + __expf(-2.f * s)) - 1.f;  // tanh
        const float z = b2f(zb_in[idx]);
        o_f[idx] = z * b2f(hb[idx]) + (1.f - z) * hh;
      }
}

// ---------------- launch ----------------
extern "C" void kernel_launch(void* const* d_in, const int* in_sizes, int n_in,
                              void* d_out, int out_size, void* d_ws, size_t ws_size,
                              hipStream_t stream) {
  const float* inputs = (const float*)d_in[0];
  const float* h_prev = (const float*)d_in[1];
  const float* Wz = (const float*)d_in[2];
  const float* Wr = (const float*)d_in[3];
  const float* Wh = (const float*)d_in[4];
  float* out = (float*)d_out;

  const int B = 16384, D = 512, U = 512, K = 1024;

  u16* xb = (u16*)d_ws;                 // [B,D] bf16
  u16* hb = xb + (size_t)B * D;         // [B,U] bf16
  u16* wzt = hb + (size_t)B * U;        // [1024,1024]: rows 0-511 Wz^T, 512-1023 Wr^T
  u16* wrt = wzt + (size_t)K * U;
  u16* wht = wrt + (size_t)K * U;       // [512,1024] Wh^T
  u16* zb = wht + (size_t)K * U;        // [B,U] bf16
  u16* rhb = zb + (size_t)B * U;        // [B,U] bf16

  const int n4 = (B * D) / 4;
  cvt_bf16_kernel<<<(n4 + 255) / 256, 256, 0, stream>>>(inputs, xb, n4);
  cvt_bf16_kernel<<<(n4 + 255) / 256, 256, 0, stream>>>(h_prev, hb, n4);
  dim3 tg((K * U + 255) / 256, 3);
  cvt_transpose_kernel<<<tg, 256, 0, stream>>>(Wz, Wr, Wh, wzt, wrt, wht, K, U);

  // gates: BM=256,BN=256 -> grid 64x4 = 256 blocks (1/CU)
  gates_k<<<dim3(256), 512, 0, stream>>>(xb, hb, wzt, zb, rhb);
  // candidate: BM=256,BN=128 -> grid 64x4 = 256 blocks (1/CU)
  cand_k<<<dim3(256), 512, 0, stream>>>(xb, rhb, wht, hb, zb, out);
}